// Round 3
// baseline (2413.420 us; speedup 1.0000x reference)
//
#include <hip/hip_runtime.h>

typedef __bf16 bf16_t;
typedef __bf16 bf16x8 __attribute__((ext_vector_type(8)));
typedef float  f32x16 __attribute__((ext_vector_type(16)));
typedef float  f32x4  __attribute__((ext_vector_type(4)));
typedef float  f32x2  __attribute__((ext_vector_type(2)));

constexpr int D_DIM  = 128;
constexpr int Q_LEN  = 4096;
constexpr int KV_LEN = 8192;
constexpr int NHEAD  = 16;
constexpr int PREFIX = KV_LEN - Q_LEN;   // 4096
constexpr int BQ     = 128;              // q rows per block (4 waves x 32)
constexpr int BKV    = 64;               // kv tile
constexpr int KP     = 136;              // K LDS pitch (bf16)
constexpr int VP     = 72;               // Vt LDS pitch (bf16)
constexpr int NROWS  = NHEAD * Q_LEN;    // 65536
constexpr size_t OSLAB = (size_t)NROWS * D_DIM;  // 8388608 floats per O slab

__device__ __forceinline__ float fast_exp2(float x) {
#if __has_builtin(__builtin_amdgcn_exp2f)
    return __builtin_amdgcn_exp2f(x);
#else
    return exp2f(x);
#endif
}

// nsplit=1: full KV range, final output to Og.  nsplit=2: bid>>9 selects KV
// half; unnormalized partial O -> Opart slab, per-row (m,l) -> Ml.
__global__ __launch_bounds__(256, 4)
void fa_fwd(const float* __restrict__ Qg, const float* __restrict__ Kg,
            const float* __restrict__ Vg, float* __restrict__ Og,
            float* __restrict__ Opart, float* __restrict__ Ml, int nsplit)
{
    __shared__ bf16_t ks[BKV * KP];        // K tile   [kv=64][d pitch 136]
    __shared__ bf16_t vt[D_DIM * VP];      // V^T tile [d=128][kv pitch 72]

    const int tid  = threadIdx.x;
    const int w    = tid >> 6;
    const int lane = tid & 63;
    const int l31  = lane & 31;            // q col (MFMA C col) / frag row
    const int H    = lane >> 5;            // lane half
    const int h8   = H * 8;
    const int h4   = H * 4;

    const int bid  = blockIdx.x;
    const int sub  = bid >> 9;             // KV half (0 when nsplit==1)
    const int pp   = bid & 511;
    // complementary pairing: pp and pp+256 get q-blocks x and 31-x
    const int half = pp >> 8;
    const int idx  = pp & 255;
    const int h    = idx & 15;
    const int qbr  = idx >> 4;
    const int qb   = half ? (31 - qbr) : qbr;
    const int q0   = qb * BQ;

    const float SCALE = 0.088388347648318447f * 1.4426950408889634f;

    // ---- Q fragments (B-operand layout: n=lane&31, k=h8+j) ----
    bf16x8 qf[8];
    {
        const float* qptr = Qg + (size_t)(h * Q_LEN + q0 + w * 32 + l31) * D_DIM + h8;
#pragma unroll
        for (int k8 = 0; k8 < 8; ++k8) {
            f32x4 a = *(const f32x4*)(qptr + k8 * 16);
            f32x4 b = *(const f32x4*)(qptr + k8 * 16 + 4);
            bf16x8 q;
            q[0] = (bf16_t)(a[0] * SCALE); q[1] = (bf16_t)(a[1] * SCALE);
            q[2] = (bf16_t)(a[2] * SCALE); q[3] = (bf16_t)(a[3] * SCALE);
            q[4] = (bf16_t)(b[0] * SCALE); q[5] = (bf16_t)(b[1] * SCALE);
            q[6] = (bf16_t)(b[2] * SCALE); q[7] = (bf16_t)(b[3] * SCALE);
            qf[k8] = q;
        }
    }

    f32x16 o_acc[4];
#pragma unroll
    for (int i = 0; i < 4; ++i) o_acc[i] = (f32x16)0.0f;
    float m_i = -1e30f, l_i = 0.0f;

    const int qpos    = PREFIX + q0 + w * 32 + l31;
    const int t_full  = (PREFIX + q0) / BKV;
    const int n_tiles = t_full + 2;
    const int t_lo    = (n_tiles * sub) / nsplit;
    const int t_hi    = (n_tiles * (sub + 1)) / nsplit;
    const size_t kvh  = (size_t)h * KV_LEN * D_DIM;

    const int kc4 = (tid & 31) * 4;   // K stage: d offset (float4)
    const int kr0 = tid >> 5;         // K stage: row base 0..7
    const int vp2 = (tid >> 3) * 2;   // V stage: even kv row
    const int vd0 = (tid & 7) * 2;    // V stage: base d (pairs, step 16)

    f32x4 kreg[8];
    f32x2 va[8], vb[8];

    auto stage_load = [&](int t) {
        const int kv0 = t * BKV;
        const float* kb = Kg + kvh + (size_t)kv0 * D_DIM;
#pragma unroll
        for (int p = 0; p < 8; ++p)
            kreg[p] = *(const f32x4*)(kb + (p * 8 + kr0) * D_DIM + kc4);
        const float* vbp = Vg + kvh + (size_t)(kv0 + vp2) * D_DIM;
#pragma unroll
        for (int g = 0; g < 8; ++g) {
            va[g] = *(const f32x2*)(vbp + vd0 + 16 * g);
            vb[g] = *(const f32x2*)(vbp + D_DIM + vd0 + 16 * g);
        }
    };

    stage_load(t_lo);

    for (int t = t_lo; t < t_hi; ++t) {
        const int kv0 = t * BKV;
        __syncthreads();
#pragma unroll
        for (int p = 0; p < 8; ++p) {
            union { bf16_t b[4]; uint2 u; } pk;
            pk.b[0] = (bf16_t)kreg[p][0]; pk.b[1] = (bf16_t)kreg[p][1];
            pk.b[2] = (bf16_t)kreg[p][2]; pk.b[3] = (bf16_t)kreg[p][3];
            *(uint2*)&ks[(p * 8 + kr0) * KP + kc4] = pk.u;
        }
#pragma unroll
        for (int g = 0; g < 8; ++g) {
            const int d = vd0 + 16 * g;
            union { bf16_t b[2]; unsigned u; } p0, p1;
            p0.b[0] = (bf16_t)va[g][0]; p0.b[1] = (bf16_t)vb[g][0];
            p1.b[0] = (bf16_t)va[g][1]; p1.b[1] = (bf16_t)vb[g][1];
            *(unsigned*)&vt[d * VP + vp2]       = p0.u;
            *(unsigned*)&vt[(d + 1) * VP + vp2] = p1.u;
        }
        __syncthreads();

        if (t + 1 < t_hi) stage_load(t + 1);

        // ---- S^T = K · Q^T ----
        f32x16 s[2];
#pragma unroll
        for (int mb = 0; mb < 2; ++mb) {
            f32x16 acc = (f32x16)0.0f;
#pragma unroll
            for (int k8 = 0; k8 < 8; ++k8) {
                bf16x8 ka = *(const bf16x8*)&ks[(mb * 32 + l31) * KP + k8 * 16 + h8];
                acc = __builtin_amdgcn_mfma_f32_32x32x16_bf16(ka, qf[k8], acc, 0, 0, 0);
            }
            s[mb] = acc;
        }

        // ---- causal mask on boundary tiles ----
        if (t >= t_full) {
#pragma unroll
            for (int mb = 0; mb < 2; ++mb)
#pragma unroll
                for (int r = 0; r < 16; ++r) {
                    const int kvg = kv0 + mb * 32 + (r & 3) + 8 * (r >> 2) + h4;
                    if (kvg > qpos) s[mb][r] = -1e30f;
                }
        }

        // ---- online softmax (paired ops to hint v_pk_*) ----
        f32x2 mt2; mt2[0] = s[0][0]; mt2[1] = s[0][1];
#pragma unroll
        for (int r2 = 1; r2 < 8; ++r2) {
            mt2[0] = fmaxf(mt2[0], s[0][2 * r2]);
            mt2[1] = fmaxf(mt2[1], s[0][2 * r2 + 1]);
        }
#pragma unroll
        for (int r2 = 0; r2 < 8; ++r2) {
            mt2[0] = fmaxf(mt2[0], s[1][2 * r2]);
            mt2[1] = fmaxf(mt2[1], s[1][2 * r2 + 1]);
        }
        float mt = fmaxf(mt2[0], mt2[1]);
        mt = fmaxf(mt, __shfl_xor(mt, 32, 64));
        const float m_new = fmaxf(m_i, mt);
        const float alpha = fast_exp2(m_i - m_new);

        unsigned pkv[16];
        f32x2 ps2 = (f32x2)0.0f;
#pragma unroll
        for (int mb = 0; mb < 2; ++mb) {
#pragma unroll
            for (int r2 = 0; r2 < 8; ++r2) {
                const float p0 = fast_exp2(s[mb][2 * r2]     - m_new);
                const float p1 = fast_exp2(s[mb][2 * r2 + 1] - m_new);
                ps2[0] += p0; ps2[1] += p1;
                union { bf16_t b[2]; unsigned u; } pk;
                pk.b[0] = (bf16_t)p0; pk.b[1] = (bf16_t)p1;
                pkv[mb * 8 + r2] = pk.u;
            }
        }
        float psum = ps2[0] + ps2[1];
        psum += __shfl_xor(psum, 32, 64);
        l_i = l_i * alpha + psum;
        m_i = m_new;

#pragma unroll
        for (int i = 0; i < 4; ++i) o_acc[i] = o_acc[i] * alpha;

        // ---- P^T B-fragments in-register (swap kv&4 groups across halves) ----
        bf16x8 pb[4];
#pragma unroll
        for (int k4 = 0; k4 < 4; ++k4) {
            const int base = (k4 >> 1) * 8 + (k4 & 1) * 4;
            const unsigned pA0 = pkv[base + 0], pA1 = pkv[base + 1];
            const unsigned pB0 = pkv[base + 2], pB1 = pkv[base + 3];
            const unsigned s0 = H ? pA0 : pB0;
            const unsigned s1 = H ? pA1 : pB1;
            const unsigned r0 = (unsigned)__shfl_xor((int)s0, 32, 64);
            const unsigned r1 = (unsigned)__shfl_xor((int)s1, 32, 64);
            union { unsigned u[4]; bf16x8 v; } fr;
            fr.u[0] = H ? r0 : pA0;
            fr.u[1] = H ? r1 : pA1;
            fr.u[2] = H ? pB0 : r0;
            fr.u[3] = H ? pB1 : r1;
            pb[k4] = fr.v;
        }

        // ---- O^T += V^T · P^T ----
#pragma unroll
        for (int mb = 0; mb < 4; ++mb) {
#pragma unroll
            for (int k4 = 0; k4 < 4; ++k4) {
                bf16x8 vaf = *(const bf16x8*)&vt[(mb * 32 + l31) * VP + k4 * 16 + h8];
                o_acc[mb] = __builtin_amdgcn_mfma_f32_32x32x16_bf16(vaf, pb[k4], o_acc[mb], 0, 0, 0);
            }
        }
    }

    const int row = h * Q_LEN + q0 + w * 32 + l31;
    if (!Opart) {
        const float inv = 1.0f / l_i;
        float* optr = Og + (size_t)row * D_DIM;
#pragma unroll
        for (int mb = 0; mb < 4; ++mb)
#pragma unroll
            for (int r = 0; r < 16; ++r) {
                const int dd = mb * 32 + (r & 3) + 8 * (r >> 2) + h4;
                optr[dd] = o_acc[mb][r] * inv;
            }
    } else {
        float* optr = Opart + (size_t)sub * OSLAB + (size_t)row * D_DIM;
#pragma unroll
        for (int mb = 0; mb < 4; ++mb)
#pragma unroll
            for (int r = 0; r < 16; ++r) {
                const int dd = mb * 32 + (r & 3) + 8 * (r >> 2) + h4;
                optr[dd] = o_acc[mb][r];
            }
        if (lane < 32) {
            Ml[(sub * 2 + 0) * NROWS + row] = m_i;
            Ml[(sub * 2 + 1) * NROWS + row] = l_i;
        }
    }
}

__global__ __launch_bounds__(256)
void fa_combine(const float* __restrict__ Opart, const float* __restrict__ Ml,
                float* __restrict__ Og)
{
    const int gid = blockIdx.x * 256 + threadIdx.x;   // 2M threads
    const int row = gid >> 5;
    const int d4  = (gid & 31) * 4;
    const float m0 = Ml[row],             l0 = Ml[NROWS + row];
    const float m1 = Ml[2 * NROWS + row], l1 = Ml[3 * NROWS + row];
    const float m  = fmaxf(m0, m1);
    const float e0 = fast_exp2(m0 - m), e1 = fast_exp2(m1 - m);
    const float inv = 1.0f / (e0 * l0 + e1 * l1);
    const float s0 = e0 * inv, s1 = e1 * inv;
    const size_t off = (size_t)row * D_DIM + d4;
    f32x4 a = *(const f32x4*)(Opart + off);
    f32x4 b = *(const f32x4*)(Opart + OSLAB + off);
    f32x4 o;
#pragma unroll
    for (int i = 0; i < 4; ++i) o[i] = s0 * a[i] + s1 * b[i];
    *(f32x4*)(Og + off) = o;
}

extern "C" void kernel_launch(void* const* d_in, const int* in_sizes, int n_in,
                              void* d_out, int out_size, void* d_ws, size_t ws_size,
                              hipStream_t stream) {
    (void)in_sizes; (void)n_in; (void)out_size;
    const float* Qg = (const float*)d_in[0];
    const float* Kg = (const float*)d_in[1];
    const float* Vg = (const float*)d_in[2];
    float* Og = (float*)d_out;

    const size_t need = (2 * OSLAB + 4 * (size_t)NROWS) * sizeof(float);
    if (ws_size >= need) {
        float* Opart = (float*)d_ws;
        float* Ml    = Opart + 2 * OSLAB;
        fa_fwd<<<dim3(1024), dim3(256), 0, stream>>>(Qg, Kg, Vg, Og, Opart, Ml, 2);
        fa_combine<<<dim3(NROWS * D_DIM / 4 / 256), dim3(256), 0, stream>>>(Opart, Ml, Og);
    } else {
        fa_fwd<<<dim3(512), dim3(256), 0, stream>>>(Qg, Kg, Vg, Og, nullptr, nullptr, 1);
    }
}

// Round 4
// 555.009 us; speedup vs baseline: 4.3484x; 4.3484x over previous
//
#include <hip/hip_runtime.h>
#include <cstdint>

typedef __bf16 bf16_t;
typedef __bf16 bf16x8 __attribute__((ext_vector_type(8)));
typedef float  f32x16 __attribute__((ext_vector_type(16)));
typedef float  f32x4  __attribute__((ext_vector_type(4)));
typedef float  f32x2  __attribute__((ext_vector_type(2)));

constexpr int D_DIM  = 128;
constexpr int Q_LEN  = 4096;
constexpr int KV_LEN = 8192;
constexpr int NHEAD  = 16;
constexpr int PREFIX = KV_LEN - Q_LEN;   // 4096
constexpr int BQ     = 128;
constexpr int BKV    = 64;
constexpr int NTILES = KV_LEN / BKV;     // 128
constexpr size_t TILEB = 16384;          // bytes per staged tile (64x128 bf16)
constexpr int NROWS  = NHEAD * Q_LEN;    // 65536
constexpr size_t OSLAB = (size_t)NROWS * D_DIM;

// legacy-path LDS pitches (fallback kernel only)
constexpr int KP = 136;
constexpr int VP = 72;

__device__ __forceinline__ float fast_exp2(float x) {
#if __has_builtin(__builtin_amdgcn_exp2f)
    return __builtin_amdgcn_exp2f(x);
#else
    return exp2f(x);
#endif
}

#define GLDS16(g, l) __builtin_amdgcn_global_load_lds(                         \
    (const __attribute__((address_space(1))) unsigned*)(g),                    \
    (__attribute__((address_space(3))) unsigned*)(l), 16, 0, 0)

// ---------------------------------------------------------------------------
// Pre-pass: K fp32 -> bf16 tiles, V fp32 -> transposed bf16 tiles, both in
// "LDS image" order with XOR swizzle baked in:
//   K tile : chunk p (16B) <-> (r=p>>4 kv-row, c=(p&15)^(r&7) d-octet)
//   Vt tile: chunk p (16B) <-> (r=p>>3 d-row,  c=(p&7)^(r&7) kv-octet)
// ---------------------------------------------------------------------------
__global__ __launch_bounds__(256)
void prep_kv(const float* __restrict__ Kg, const float* __restrict__ Vg,
             char* __restrict__ KbfB, char* __restrict__ VtB)
{
    const int bid = blockIdx.x;
    const int tid = threadIdx.x;
    __shared__ bf16_t ld[BKV][D_DIM + 4];

    if (bid < NHEAD * NTILES) {
        const int h = bid / NTILES, t = bid % NTILES;
        const float* src = Kg + ((size_t)h * KV_LEN + (size_t)t * BKV) * D_DIM;
        char* dst = KbfB + (size_t)bid * TILEB;
#pragma unroll
        for (int j = 0; j < 4; ++j) {
            const int p = tid * 4 + j;
            const int r = p >> 4;
            const int c = (p & 15) ^ (r & 7);
            f32x4 a = *(const f32x4*)(src + r * D_DIM + c * 8);
            f32x4 b = *(const f32x4*)(src + r * D_DIM + c * 8 + 4);
            union { bf16_t h[8]; uint4 u; } pk;
            pk.h[0] = (bf16_t)a[0]; pk.h[1] = (bf16_t)a[1];
            pk.h[2] = (bf16_t)a[2]; pk.h[3] = (bf16_t)a[3];
            pk.h[4] = (bf16_t)b[0]; pk.h[5] = (bf16_t)b[1];
            pk.h[6] = (bf16_t)b[2]; pk.h[7] = (bf16_t)b[3];
            *(uint4*)(dst + (size_t)p * 16) = pk.u;
        }
    } else {
        const int b2 = bid - NHEAD * NTILES;
        const int h = b2 / NTILES, t = b2 % NTILES;
        const float* src = Vg + ((size_t)h * KV_LEN + (size_t)t * BKV) * D_DIM;
        char* dst = VtB + (size_t)b2 * TILEB;
        {
            const int row = tid >> 2, c0 = (tid & 3) * 32;
#pragma unroll
            for (int g = 0; g < 8; ++g) {
                f32x4 a = *(const f32x4*)(src + row * D_DIM + c0 + g * 4);
                ld[row][c0 + g * 4 + 0] = (bf16_t)a[0];
                ld[row][c0 + g * 4 + 1] = (bf16_t)a[1];
                ld[row][c0 + g * 4 + 2] = (bf16_t)a[2];
                ld[row][c0 + g * 4 + 3] = (bf16_t)a[3];
            }
        }
        __syncthreads();
#pragma unroll
        for (int j = 0; j < 4; ++j) {
            const int p = tid * 4 + j;
            const int r = p >> 3;                 // d row 0..127
            const int c = (p & 7) ^ (r & 7);      // kv octet
            union { bf16_t h[8]; uint4 u; } pk;
#pragma unroll
            for (int i = 0; i < 8; ++i) pk.h[i] = ld[c * 8 + i][r];
            *(uint4*)(dst + (size_t)p * 16) = pk.u;
        }
    }
}

// ---------------------------------------------------------------------------
// Main flash kernel, prebaked bf16 tiles, async LDS staging, split-KV x2.
// grid 1024: bid>>9 = KV half, low 9 bits decode (h, q-block) with
// complementary pairing for causal load balance.
// ---------------------------------------------------------------------------
__global__ __launch_bounds__(256, 3)
void fa_fwd_pre(const float* __restrict__ Qg, const char* __restrict__ KbfB,
                const char* __restrict__ VtB, float* __restrict__ Opart,
                float* __restrict__ Ml)
{
    __shared__ __align__(16) char ksm[TILEB];   // K tile image
    __shared__ __align__(16) char vsm[TILEB];   // V^T tile image

    const int tid  = threadIdx.x;
    const int w    = tid >> 6;
    const int lane = tid & 63;
    const int l31  = lane & 31;
    const int H    = lane >> 5;
    const int h8   = H * 8;
    const int h4   = H * 4;
    const int swz  = l31 & 7;

    const int bid  = blockIdx.x;
    const int sub  = bid >> 9;
    const int pp   = bid & 511;
    const int half = pp >> 8;
    const int idx  = pp & 255;
    const int h    = idx & 15;
    const int qbr  = idx >> 4;
    const int qb   = half ? (31 - qbr) : qbr;
    const int q0   = qb * BQ;

    const float SCALE = 0.088388347648318447f * 1.4426950408889634f;

    // ---- Q fragments (B-operand layout: n=lane&31, k=h8+j) ----
    bf16x8 qf[8];
    {
        const float* qptr = Qg + (size_t)(h * Q_LEN + q0 + w * 32 + l31) * D_DIM + h8;
#pragma unroll
        for (int k8 = 0; k8 < 8; ++k8) {
            f32x4 a = *(const f32x4*)(qptr + k8 * 16);
            f32x4 b = *(const f32x4*)(qptr + k8 * 16 + 4);
            bf16x8 q;
            q[0] = (bf16_t)(a[0] * SCALE); q[1] = (bf16_t)(a[1] * SCALE);
            q[2] = (bf16_t)(a[2] * SCALE); q[3] = (bf16_t)(a[3] * SCALE);
            q[4] = (bf16_t)(b[0] * SCALE); q[5] = (bf16_t)(b[1] * SCALE);
            q[6] = (bf16_t)(b[2] * SCALE); q[7] = (bf16_t)(b[3] * SCALE);
            qf[k8] = q;
        }
    }

    f32x16 o_acc[4];
#pragma unroll
    for (int i = 0; i < 4; ++i) o_acc[i] = (f32x16)0.0f;
    float m_i = -1e30f, l_i = 0.0f;

    const int qpos    = PREFIX + q0 + w * 32 + l31;
    const int t_full  = (PREFIX + q0) / BKV;
    const int n_tiles = t_full + 2;
    const int t_lo    = (n_tiles * sub) >> 1;
    const int t_hi    = (n_tiles * (sub + 1)) >> 1;

    const char* ksrc = KbfB + (size_t)(h * NTILES) * TILEB;
    const char* vsrc = VtB  + (size_t)(h * NTILES) * TILEB;
    const int soff = w * 4096 + lane * 16;   // this lane's DMA source offset

    for (int t = t_lo; t < t_hi; ++t) {
        const int kv0 = t * BKV;
        __syncthreads();                      // previous tile fully consumed
        {
            const char* kg = ksrc + (size_t)t * TILEB + soff;
            const char* vg = vsrc + (size_t)t * TILEB + soff;
#pragma unroll
            for (int j = 0; j < 4; ++j) {
                GLDS16(kg + j * 1024, ksm + w * 4096 + j * 1024);
                GLDS16(vg + j * 1024, vsm + w * 4096 + j * 1024);
            }
        }
        __syncthreads();                      // DMA drained: tile visible

        // ---- S^T = K · Q^T ----
        f32x16 s[2];
#pragma unroll
        for (int mb = 0; mb < 2; ++mb) {
            f32x16 acc = (f32x16)0.0f;
#pragma unroll
            for (int k8 = 0; k8 < 8; ++k8) {
                const int off = mb * 8192 + l31 * 256 + (((k8 * 2 + H) ^ swz) << 4);
                bf16x8 ka = *(const bf16x8*)(ksm + off);
                acc = __builtin_amdgcn_mfma_f32_32x32x16_bf16(ka, qf[k8], acc, 0, 0, 0);
            }
            s[mb] = acc;
        }

        // ---- causal mask on boundary tiles ----
        if (t >= t_full) {
#pragma unroll
            for (int mb = 0; mb < 2; ++mb)
#pragma unroll
                for (int r = 0; r < 16; ++r) {
                    const int kvg = kv0 + mb * 32 + (r & 3) + 8 * (r >> 2) + h4;
                    if (kvg > qpos) s[mb][r] = -1e30f;
                }
        }

        // ---- online softmax (per-lane scalar stats) ----
        f32x2 mt2; mt2[0] = s[0][0]; mt2[1] = s[0][1];
#pragma unroll
        for (int r2 = 1; r2 < 8; ++r2) {
            mt2[0] = fmaxf(mt2[0], s[0][2 * r2]);
            mt2[1] = fmaxf(mt2[1], s[0][2 * r2 + 1]);
        }
#pragma unroll
        for (int r2 = 0; r2 < 8; ++r2) {
            mt2[0] = fmaxf(mt2[0], s[1][2 * r2]);
            mt2[1] = fmaxf(mt2[1], s[1][2 * r2 + 1]);
        }
        float mt = fmaxf(mt2[0], mt2[1]);
        mt = fmaxf(mt, __shfl_xor(mt, 32, 64));
        const float m_new = fmaxf(m_i, mt);
        const float alpha = fast_exp2(m_i - m_new);

        unsigned pkv[16];
        f32x2 ps2 = (f32x2)0.0f;
#pragma unroll
        for (int mb = 0; mb < 2; ++mb) {
#pragma unroll
            for (int r2 = 0; r2 < 8; ++r2) {
                const float p0 = fast_exp2(s[mb][2 * r2]     - m_new);
                const float p1 = fast_exp2(s[mb][2 * r2 + 1] - m_new);
                ps2[0] += p0; ps2[1] += p1;
                union { bf16_t b[2]; unsigned u; } pk;
                pk.b[0] = (bf16_t)p0; pk.b[1] = (bf16_t)p1;
                pkv[mb * 8 + r2] = pk.u;
            }
        }
        float psum = ps2[0] + ps2[1];
        psum += __shfl_xor(psum, 32, 64);
        l_i = l_i * alpha + psum;
        m_i = m_new;

        if (__any(alpha != 1.0f)) {
#pragma unroll
            for (int i = 0; i < 4; ++i) o_acc[i] = o_acc[i] * alpha;
        }

        // ---- P^T B-fragments in-register (swap kv&4 groups across halves) ----
        bf16x8 pb[4];
#pragma unroll
        for (int k4 = 0; k4 < 4; ++k4) {
            const int base = (k4 >> 1) * 8 + (k4 & 1) * 4;
            const unsigned pA0 = pkv[base + 0], pA1 = pkv[base + 1];
            const unsigned pB0 = pkv[base + 2], pB1 = pkv[base + 3];
            const unsigned s0 = H ? pA0 : pB0;
            const unsigned s1 = H ? pA1 : pB1;
            const unsigned r0 = (unsigned)__shfl_xor((int)s0, 32, 64);
            const unsigned r1 = (unsigned)__shfl_xor((int)s1, 32, 64);
            union { unsigned u[4]; bf16x8 v; } fr;
            fr.u[0] = H ? r0 : pA0;
            fr.u[1] = H ? r1 : pA1;
            fr.u[2] = H ? pB0 : r0;
            fr.u[3] = H ? pB1 : r1;
            pb[k4] = fr.v;
        }

        // ---- O^T += V^T · P^T ----
#pragma unroll
        for (int mb = 0; mb < 4; ++mb) {
#pragma unroll
            for (int k4 = 0; k4 < 4; ++k4) {
                const int off = mb * 4096 + l31 * 128 + (((k4 * 2 + H) ^ swz) << 4);
                bf16x8 vaf = *(const bf16x8*)(vsm + off);
                o_acc[mb] = __builtin_amdgcn_mfma_f32_32x32x16_bf16(vaf, pb[k4], o_acc[mb], 0, 0, 0);
            }
        }
    }

    const int row = h * Q_LEN + q0 + w * 32 + l31;
    float* optr = Opart + (size_t)sub * OSLAB + (size_t)row * D_DIM;
#pragma unroll
    for (int mb = 0; mb < 4; ++mb)
#pragma unroll
        for (int r = 0; r < 16; ++r) {
            const int dd = mb * 32 + (r & 3) + 8 * (r >> 2) + h4;
            optr[dd] = o_acc[mb][r];
        }
    if (H == 0) {
        Ml[(sub * 2 + 0) * NROWS + row] = m_i;
        Ml[(sub * 2 + 1) * NROWS + row] = l_i;
    }
}

__global__ __launch_bounds__(256)
void fa_combine(const float* __restrict__ Opart, const float* __restrict__ Ml,
                float* __restrict__ Og)
{
    const int gid = blockIdx.x * 256 + threadIdx.x;
    const int row = gid >> 5;
    const int d4  = (gid & 31) * 4;
    const float m0 = Ml[row],             l0 = Ml[NROWS + row];
    const float m1 = Ml[2 * NROWS + row], l1 = Ml[3 * NROWS + row];
    const float m  = fmaxf(m0, m1);
    const float e0 = fast_exp2(m0 - m), e1 = fast_exp2(m1 - m);
    const float inv = 1.0f / (e0 * l0 + e1 * l1);
    const float s0 = e0 * inv, s1 = e1 * inv;
    const size_t off = (size_t)row * D_DIM + d4;
    f32x4 a = *(const f32x4*)(Opart + off);
    f32x4 b = *(const f32x4*)(Opart + OSLAB + off);
    f32x4 o;
#pragma unroll
    for (int i = 0; i < 4; ++i) o[i] = s0 * a[i] + s1 * b[i];
    *(f32x4*)(Og + off) = o;
}

// ---------------------------------------------------------------------------
// Fallback (proven R2 kernel): direct fp32 staging, no workspace, grid 512.
// ---------------------------------------------------------------------------
__global__ __launch_bounds__(256, 2)
void fa_fwd_direct(const float* __restrict__ Qg, const float* __restrict__ Kg,
                   const float* __restrict__ Vg, float* __restrict__ Og)
{
    __shared__ bf16_t ks[BKV * KP];
    __shared__ bf16_t vt[D_DIM * VP];

    const int tid  = threadIdx.x;
    const int w    = tid >> 6;
    const int lane = tid & 63;
    const int l31  = lane & 31;
    const int H    = lane >> 5;
    const int h8   = H * 8;
    const int h4   = H * 4;

    const int bid  = blockIdx.x;
    const int half = bid >> 8;
    const int idx  = bid & 255;
    const int h    = idx & 15;
    const int qbr  = idx >> 4;
    const int qb   = half ? (31 - qbr) : qbr;
    const int q0   = qb * BQ;

    const float SCALE = 0.088388347648318447f * 1.4426950408889634f;

    bf16x8 qf[8];
    {
        const float* qptr = Qg + (size_t)(h * Q_LEN + q0 + w * 32 + l31) * D_DIM + h8;
#pragma unroll
        for (int k8 = 0; k8 < 8; ++k8) {
            f32x4 a = *(const f32x4*)(qptr + k8 * 16);
            f32x4 b = *(const f32x4*)(qptr + k8 * 16 + 4);
            bf16x8 q;
            q[0] = (bf16_t)(a[0] * SCALE); q[1] = (bf16_t)(a[1] * SCALE);
            q[2] = (bf16_t)(a[2] * SCALE); q[3] = (bf16_t)(a[3] * SCALE);
            q[4] = (bf16_t)(b[0] * SCALE); q[5] = (bf16_t)(b[1] * SCALE);
            q[6] = (bf16_t)(b[2] * SCALE); q[7] = (bf16_t)(b[3] * SCALE);
            qf[k8] = q;
        }
    }

    f32x16 o_acc[4];
#pragma unroll
    for (int i = 0; i < 4; ++i) o_acc[i] = (f32x16)0.0f;
    float m_i = -1e30f, l_i = 0.0f;

    const int qpos    = PREFIX + q0 + w * 32 + l31;
    const int t_full  = (PREFIX + q0) / BKV;
    const int n_tiles = t_full + 2;
    const size_t kvh  = (size_t)h * KV_LEN * D_DIM;

    const int kc4 = (tid & 31) * 4;
    const int kr0 = tid >> 5;
    const int vp2 = (tid >> 3) * 2;
    const int vd0 = (tid & 7) * 2;

    f32x4 kreg[8];
    f32x2 va[8], vb[8];

    auto stage_load = [&](int t) {
        const int kv0 = t * BKV;
        const float* kb = Kg + kvh + (size_t)kv0 * D_DIM;
#pragma unroll
        for (int p = 0; p < 8; ++p)
            kreg[p] = *(const f32x4*)(kb + (p * 8 + kr0) * D_DIM + kc4);
        const float* vbp = Vg + kvh + (size_t)(kv0 + vp2) * D_DIM;
#pragma unroll
        for (int g = 0; g < 8; ++g) {
            va[g] = *(const f32x2*)(vbp + vd0 + 16 * g);
            vb[g] = *(const f32x2*)(vbp + D_DIM + vd0 + 16 * g);
        }
    };

    stage_load(0);

    for (int t = 0; t < n_tiles; ++t) {
        const int kv0 = t * BKV;
        __syncthreads();
#pragma unroll
        for (int p = 0; p < 8; ++p) {
            union { bf16_t b[4]; uint2 u; } pk;
            pk.b[0] = (bf16_t)kreg[p][0]; pk.b[1] = (bf16_t)kreg[p][1];
            pk.b[2] = (bf16_t)kreg[p][2]; pk.b[3] = (bf16_t)kreg[p][3];
            *(uint2*)&ks[(p * 8 + kr0) * KP + kc4] = pk.u;
        }
#pragma unroll
        for (int g = 0; g < 8; ++g) {
            const int d = vd0 + 16 * g;
            union { bf16_t b[2]; unsigned u; } p0, p1;
            p0.b[0] = (bf16_t)va[g][0]; p0.b[1] = (bf16_t)vb[g][0];
            p1.b[0] = (bf16_t)va[g][1]; p1.b[1] = (bf16_t)vb[g][1];
            *(unsigned*)&vt[d * VP + vp2]       = p0.u;
            *(unsigned*)&vt[(d + 1) * VP + vp2] = p1.u;
        }
        __syncthreads();

        if (t + 1 < n_tiles) stage_load(t + 1);

        f32x16 s[2];
#pragma unroll
        for (int mb = 0; mb < 2; ++mb) {
            f32x16 acc = (f32x16)0.0f;
#pragma unroll
            for (int k8 = 0; k8 < 8; ++k8) {
                bf16x8 ka = *(const bf16x8*)&ks[(mb * 32 + l31) * KP + k8 * 16 + h8];
                acc = __builtin_amdgcn_mfma_f32_32x32x16_bf16(ka, qf[k8], acc, 0, 0, 0);
            }
            s[mb] = acc;
        }

        if (t >= t_full) {
#pragma unroll
            for (int mb = 0; mb < 2; ++mb)
#pragma unroll
                for (int r = 0; r < 16; ++r) {
                    const int kvg = kv0 + mb * 32 + (r & 3) + 8 * (r >> 2) + h4;
                    if (kvg > qpos) s[mb][r] = -1e30f;
                }
        }

        float mt = s[0][0];
#pragma unroll
        for (int r = 1; r < 16; ++r) mt = fmaxf(mt, s[0][r]);
#pragma unroll
        for (int r = 0; r < 16; ++r) mt = fmaxf(mt, s[1][r]);
        mt = fmaxf(mt, __shfl_xor(mt, 32, 64));
        const float m_new = fmaxf(m_i, mt);
        const float alpha = fast_exp2(m_i - m_new);

        unsigned pkv[16];
        float psum = 0.0f;
#pragma unroll
        for (int mb = 0; mb < 2; ++mb) {
#pragma unroll
            for (int r2 = 0; r2 < 8; ++r2) {
                const float p0 = fast_exp2(s[mb][2 * r2]     - m_new);
                const float p1 = fast_exp2(s[mb][2 * r2 + 1] - m_new);
                psum += p0 + p1;
                union { bf16_t b[2]; unsigned u; } pk;
                pk.b[0] = (bf16_t)p0; pk.b[1] = (bf16_t)p1;
                pkv[mb * 8 + r2] = pk.u;
            }
        }
        psum += __shfl_xor(psum, 32, 64);
        l_i = l_i * alpha + psum;
        m_i = m_new;

#pragma unroll
        for (int i = 0; i < 4; ++i) o_acc[i] = o_acc[i] * alpha;

        bf16x8 pb[4];
#pragma unroll
        for (int k4 = 0; k4 < 4; ++k4) {
            const int base = (k4 >> 1) * 8 + (k4 & 1) * 4;
            const unsigned pA0 = pkv[base + 0], pA1 = pkv[base + 1];
            const unsigned pB0 = pkv[base + 2], pB1 = pkv[base + 3];
            const unsigned s0 = H ? pA0 : pB0;
            const unsigned s1 = H ? pA1 : pB1;
            const unsigned r0 = (unsigned)__shfl_xor((int)s0, 32, 64);
            const unsigned r1 = (unsigned)__shfl_xor((int)s1, 32, 64);
            union { unsigned u[4]; bf16x8 v; } fr;
            fr.u[0] = H ? r0 : pA0;
            fr.u[1] = H ? r1 : pA1;
            fr.u[2] = H ? pB0 : r0;
            fr.u[3] = H ? pB1 : r1;
            pb[k4] = fr.v;
        }

#pragma unroll
        for (int mb = 0; mb < 4; ++mb) {
#pragma unroll
            for (int k4 = 0; k4 < 4; ++k4) {
                bf16x8 vaf = *(const bf16x8*)&vt[(mb * 32 + l31) * VP + k4 * 16 + h8];
                o_acc[mb] = __builtin_amdgcn_mfma_f32_32x32x16_bf16(vaf, pb[k4], o_acc[mb], 0, 0, 0);
            }
        }
    }

    const float inv = 1.0f / l_i;
    float* optr = Og + (size_t)(h * Q_LEN + q0 + w * 32 + l31) * D_DIM;
#pragma unroll
    for (int mb = 0; mb < 4; ++mb)
#pragma unroll
        for (int r = 0; r < 16; ++r) {
            const int dd = mb * 32 + (r & 3) + 8 * (r >> 2) + h4;
            optr[dd] = o_acc[mb][r] * inv;
        }
}

extern "C" void kernel_launch(void* const* d_in, const int* in_sizes, int n_in,
                              void* d_out, int out_size, void* d_ws, size_t ws_size,
                              hipStream_t stream) {
    (void)in_sizes; (void)n_in; (void)out_size;
    const float* Qg = (const float*)d_in[0];
    const float* Kg = (const float*)d_in[1];
    const float* Vg = (const float*)d_in[2];
    float* Og = (float*)d_out;

    const size_t kvbytes = (size_t)NHEAD * NTILES * TILEB;           // 32 MB each
    const size_t need = 2 * kvbytes + (2 * OSLAB + 4 * (size_t)NROWS) * sizeof(float);
    if (ws_size >= need) {
        char* KbfB   = (char*)d_ws;
        char* VtB    = KbfB + kvbytes;
        float* Opart = (float*)(VtB + kvbytes);
        float* Ml    = Opart + 2 * OSLAB;
        prep_kv<<<dim3(2 * NHEAD * NTILES), dim3(256), 0, stream>>>(Kg, Vg, KbfB, VtB);
        fa_fwd_pre<<<dim3(1024), dim3(256), 0, stream>>>(Qg, KbfB, VtB, Opart, Ml);
        fa_combine<<<dim3(NROWS * D_DIM / 4 / 256), dim3(256), 0, stream>>>(Opart, Ml, Og);
    } else {
        fa_fwd_direct<<<dim3(512), dim3(256), 0, stream>>>(Qg, Kg, Vg, Og);
    }
}